// Round 2
// baseline (8535.299 us; speedup 1.0000x reference)
//
#include <hip/hip_runtime.h>

// TimeLSTM persistent kernel for MI355X (gfx950).
// B=128, S=512, I=256, H=512.
// Structure: 256 blocks x 256 threads, PLAIN launch (grid == CU count -> all
// blocks trivially co-resident; no cooperative-launch dependency).
//   group gq = blockIdx%8  -> batch rows [gq*16, gq*16+16)   (8 independent groups)
//   slice s  = blockIdx/8  -> H columns  [s*16, s*16+16)     (32 slices/group)
// Weight-stationary: each wave holds its B-fragments (bf16) in VGPRs:
//   wave w: gate-w rows of W_all (K=512), gate-w rows of U_all (K=256),
//           plus a K-quarter of W_d (partials reduced through LDS).
// h/c exchanged per step through double-buffered global bf16 arrays + per-group
// device-scope spin barrier (monotone counter, no sense reversal needed).
// x (fp32) is staged to LDS per step and converted to bf16 in-LDS (no big
// workspace needed: total d_ws use is 0.51 MB).

#define Bq 128
#define Sq 512
#define Iq 256
#define Hq 512

typedef __bf16  bf16x8  __attribute__((ext_vector_type(8)));
typedef float   floatx4 __attribute__((ext_vector_type(4)));
typedef unsigned short ushort;
typedef ushort  ushort8 __attribute__((ext_vector_type(8)));

__device__ __forceinline__ ushort f2bf(float f) {
    union { float f; unsigned u; } v; v.f = f;
    unsigned r = v.u + 0x7fffu + ((v.u >> 16) & 1u);   // RNE
    return (ushort)(r >> 16);
}

__device__ __forceinline__ float sigm(float x) { return 1.f / (1.f + __expf(-x)); }
__device__ __forceinline__ float tanh_fast(float x) {
    float e = __expf(2.f * x);
    return 1.f - 2.f / (e + 1.f);
}

__device__ __forceinline__ void gl_lds16(const void* g, void* l) {
    __builtin_amdgcn_global_load_lds(
        (const __attribute__((address_space(1))) unsigned int*)g,
        (__attribute__((address_space(3))) unsigned int*)l, 16, 0, 0);
}

__device__ __forceinline__ bf16x8 pack8(float4 a, float4 b) {
    ushort8 v;
    v[0] = f2bf(a.x); v[1] = f2bf(a.y); v[2] = f2bf(a.z); v[3] = f2bf(a.w);
    v[4] = f2bf(b.x); v[5] = f2bf(b.y); v[6] = f2bf(b.z); v[7] = f2bf(b.w);
    return __builtin_bit_cast(bf16x8, v);
}

// ---------------- main persistent kernel ----------------
__global__ __launch_bounds__(256, 1) void lstm_kernel(
    const float* __restrict__ xin,
    const float* __restrict__ tsp,
    const float* __restrict__ Ww, const float* __restrict__ Wb,
    const float* __restrict__ Uw, const float* __restrict__ Ub,
    const float* __restrict__ Dw, const float* __restrict__ Db,
    ushort* __restrict__ hbuf, ushort* __restrict__ cbuf,
    unsigned int* __restrict__ cnt, float* __restrict__ out)
{
    __shared__ ushort h_s[16 * 520];   // rows padded +8 bf16 (16B) to keep 2-way-max bank aliasing
    __shared__ ushort c_s[16 * 520];
    __shared__ ushort x_s[16 * 264];   // bf16 x tile
    __shared__ float  x32_s[16 * 260]; // fp32 x staging (padded +4 floats)
    __shared__ float  gb[4 * 256];     // gate preactivations (one tile per wave/gate)
    __shared__ float  gd[4 * 256];     // W_d K-quarter partials
    __shared__ float  bias_g[64];      // W_all_b + U_all_b for this slice, [gate][16]
    __shared__ float  bias_d[16];

    const int tid  = threadIdx.x;
    const int lane = tid & 63;
    const int wv   = tid >> 6;         // wave id 0..3 == gate id
    const int n    = lane & 15;        // MFMA A-row (m) / B-col (n) index
    const int quad = lane >> 4;
    const int gq   = blockIdx.x & 7;   // batch group
    const int s    = blockIdx.x >> 3;  // column slice
    const int jj   = s * 16;

    // ---- load stationary B-fragments (once) ----
    bf16x8 bW[16], bU[8], bD[4];
    {
        const int Rw = wv * Hq + jj + n;            // row of W_all / U_all (gate wv)
        #pragma unroll
        for (int kk = 0; kk < 16; ++kk) {
            const float4* p = (const float4*)(Ww + (size_t)Rw * Hq + kk * 32 + quad * 8);
            bW[kk] = pack8(p[0], p[1]);
        }
        #pragma unroll
        for (int kk = 0; kk < 8; ++kk) {
            const float4* p = (const float4*)(Uw + (size_t)Rw * Iq + kk * 32 + quad * 8);
            bU[kk] = pack8(p[0], p[1]);
        }
        const int Rd = jj + n;
        #pragma unroll
        for (int kq = 0; kq < 4; ++kq) {
            const float4* p = (const float4*)(Dw + (size_t)Rd * Hq + (wv * 4 + kq) * 32 + quad * 8);
            bD[kq] = pack8(p[0], p[1]);
        }
    }
    if (tid < 64)
        bias_g[tid] = Wb[(tid >> 4) * Hq + jj + (tid & 15)] + Ub[(tid >> 4) * Hq + jj + (tid & 15)];
    if (tid >= 64 && tid < 80)
        bias_d[tid - 64] = Db[jj + (tid - 64)];
    __syncthreads();

    float c_reg = 0.f;                 // this thread's fp32 cell state, (b=tid>>4, j=tid&15)
    const int b = tid >> 4, j = tid & 15;
    const int grow = gq * 16 + b;

    const ushort* hp = &h_s[n * 520 + quad * 8];
    const ushort* cp = &c_s[n * 520 + quad * 8];
    const ushort* xp = &x_s[n * 264 + quad * 8];

    for (int t = 0; t < Sq; ++t) {
        // timestamp load (hidden behind staging + MFMA)
        float tt = tsp[(size_t)grow * Sq + t];

        // ---- stage h, c (prev step, parity t&1) and fp32 x(t) into LDS ----
        const ushort* hsrc = hbuf + (t & 1) * (Bq * Hq);
        const ushort* csrc = cbuf + (t & 1) * (Bq * Hq);
        #pragma unroll
        for (int q = 0; q < 4; ++q) {
            int r = q * 4 + wv;
            gl_lds16(hsrc + (size_t)(gq * 16 + r) * Hq + lane * 8, &h_s[r * 520]);
            gl_lds16(csrc + (size_t)(gq * 16 + r) * Hq + lane * 8, &c_s[r * 520]);
            gl_lds16(xin + ((size_t)(gq * 16 + r) * Sq + t) * Iq + lane * 4, &x32_s[r * 260]);
        }
        __syncthreads();

        // ---- convert fp32 x tile -> bf16 x_s (thread tid: row tid>>4, 16 cols) ----
        {
            const int rr = tid >> 4, seg = tid & 15;
            const float4* src = (const float4*)&x32_s[rr * 260 + seg * 16];
            float4 a0 = src[0], a1 = src[1], a2 = src[2], a3 = src[3];
            ushort8 v0, v1;
            v0[0] = f2bf(a0.x); v0[1] = f2bf(a0.y); v0[2] = f2bf(a0.z); v0[3] = f2bf(a0.w);
            v0[4] = f2bf(a1.x); v0[5] = f2bf(a1.y); v0[6] = f2bf(a1.z); v0[7] = f2bf(a1.w);
            v1[0] = f2bf(a2.x); v1[1] = f2bf(a2.y); v1[2] = f2bf(a2.z); v1[3] = f2bf(a2.w);
            v1[4] = f2bf(a3.x); v1[5] = f2bf(a3.y); v1[6] = f2bf(a3.z); v1[7] = f2bf(a3.w);
            *(ushort8*)&x_s[rr * 264 + seg * 16]     = v0;
            *(ushort8*)&x_s[rr * 264 + seg * 16 + 8] = v1;
        }
        __syncthreads();

        // ---- MFMA phase ----
        floatx4 accW = {0.f, 0.f, 0.f, 0.f};
        floatx4 accU = {0.f, 0.f, 0.f, 0.f};
        floatx4 accD = {0.f, 0.f, 0.f, 0.f};
        #pragma unroll
        for (int kk = 0; kk < 16; ++kk) {
            bf16x8 ah = *(const bf16x8*)(hp + kk * 32);
            accW = __builtin_amdgcn_mfma_f32_16x16x32_bf16(ah, bW[kk], accW, 0, 0, 0);
            if (kk < 8) {
                bf16x8 ax = *(const bf16x8*)(xp + kk * 32);
                accU = __builtin_amdgcn_mfma_f32_16x16x32_bf16(ax, bU[kk], accU, 0, 0, 0);
            }
            if ((kk >> 2) == wv) {
                bf16x8 ac = *(const bf16x8*)(cp + kk * 32);
                accD = __builtin_amdgcn_mfma_f32_16x16x32_bf16(ac, bD[kk & 3], accD, 0, 0, 0);
            }
        }
        accW += accU;

        #pragma unroll
        for (int r2 = 0; r2 < 4; ++r2) {
            gb[wv * 256 + (quad * 4 + r2) * 16 + n] = accW[r2];
            gd[wv * 256 + (quad * 4 + r2) * 16 + n] = accD[r2];
        }
        __syncthreads();

        // ---- gate math: thread (b, j) ----
        float pf = gb[tid]       + bias_g[j];
        float pi = gb[256 + tid] + bias_g[16 + j];
        float po = gb[512 + tid] + bias_g[32 + j];
        float pc = gb[768 + tid] + bias_g[48 + j];
        float csum = gd[tid] + gd[256 + tid] + gd[512 + tid] + gd[768 + tid] + bias_d[j];
        float c_s1  = tanh_fast(csum);
        float c_adj = c_reg - c_s1 + c_s1 * tt;
        float fg = sigm(pf), ig = sigm(pi), og = sigm(po), cg = sigm(pc);
        float c_new = fg * c_adj + ig * cg;
        float h_new = og * tanh_fast(c_new);
        c_reg = c_new;

        ushort* hdst = hbuf + ((t + 1) & 1) * (Bq * Hq);
        ushort* cdst = cbuf + ((t + 1) & 1) * (Bq * Hq);
        hdst[(size_t)grow * Hq + jj + j] = f2bf(h_new);
        cdst[(size_t)grow * Hq + jj + j] = f2bf(c_new);
        out[((size_t)grow * Sq + t) * Hq + jj + j] = h_new;
        __syncthreads();   // drains the global writes (vmcnt) for all waves

        // ---- per-group inter-WG barrier (skip after last step) ----
        if (t < Sq - 1) {
            if (tid == 0) {
                __threadfence();   // release: L2 writeback, cross-XCD visibility
                __hip_atomic_fetch_add(&cnt[gq * 64], 1u, __ATOMIC_RELEASE, __HIP_MEMORY_SCOPE_AGENT);
                unsigned target = 32u * (unsigned)(t + 1);
                while (__hip_atomic_load(&cnt[gq * 64], __ATOMIC_RELAXED, __HIP_MEMORY_SCOPE_AGENT) < target)
                    __builtin_amdgcn_s_sleep(1);
                __threadfence();   // acquire: invalidate caches before re-reading h/c
            }
            __syncthreads();
        }
    }
}

extern "C" void kernel_launch(void* const* d_in, const int* in_sizes, int n_in,
                              void* d_out, int out_size, void* d_ws, size_t ws_size,
                              hipStream_t stream) {
    const float* inputs = (const float*)d_in[0];
    const float* tsp    = (const float*)d_in[1];
    const float* Ww     = (const float*)d_in[2];
    const float* Wb     = (const float*)d_in[3];
    const float* Uw     = (const float*)d_in[4];
    const float* Ub     = (const float*)d_in[5];
    const float* Dw     = (const float*)d_in[6];
    const float* Db     = (const float*)d_in[7];
    float* out = (float*)d_out;

    char* ws = (char*)d_ws;
    // layout: [0,262144) hbuf (2 parities) | [262144,524288) cbuf | [524288,526336) cnt
    ushort*       hbuf = (ushort*)ws;
    ushort*       cbuf = (ushort*)(ws + 262144);
    unsigned int* cnt  = (unsigned int*)(ws + 524288);

    hipMemsetAsync(ws, 0, 526336, stream);   // h0=c0=0 (bf16 zero == 0x0000), barrier counters = 0

    lstm_kernel<<<dim3(256), dim3(256), 0, stream>>>(
        inputs, tsp, Ww, Wb, Uw, Ub, Dw, Db, hbuf, cbuf, cnt, out);
}

// Round 3
// 2233.365 us; speedup vs baseline: 3.8217x; 3.8217x over previous
//
#include <hip/hip_runtime.h>

// TimeLSTM persistent kernel for MI355X (gfx950).  B=128, S=512, I=256, H=512.
// 256 blocks x 256 threads, plain launch (grid == CU count -> co-resident).
//   group gq = blockIdx%8 -> batch rows [gq*16, gq*16+16)  (8 independent groups)
//   slice s  = blockIdx/8 -> H columns [s*16, s*16+16)     (32 slices/group)
// Weight-stationary (112 VGPRs of bf16 B-fragments per wave).
// Cross-block h/c exchange: packed u32 (c<<16|h), RELAXED AGENT-scope atomics
// (sc1: write-through / L2-bypass) -- NO threadfence (no buffer_wbl2/inv),
// NO contended RMW counter. Per-group 32-slot flag array, one writer per slot,
// parallel poll by wave 0. Ordering via the vmcnt(0) drain at __syncthreads().

#define Bq 128
#define Sq 512
#define Iq 256
#define Hq 512

typedef __bf16  bf16x8  __attribute__((ext_vector_type(8)));
typedef float   floatx4 __attribute__((ext_vector_type(4)));
typedef unsigned short ushort;
typedef ushort  ushort8 __attribute__((ext_vector_type(8)));

__device__ __forceinline__ ushort f2bf(float f) {
    union { float f; unsigned u; } v; v.f = f;
    unsigned r = v.u + 0x7fffu + ((v.u >> 16) & 1u);   // RNE
    return (ushort)(r >> 16);
}

__device__ __forceinline__ float sigm(float x) { return 1.f / (1.f + __expf(-x)); }
__device__ __forceinline__ float tanh_fast(float x) {
    float e = __expf(2.f * x);
    return 1.f - 2.f / (e + 1.f);
}

__device__ __forceinline__ void gl_lds16(const void* g, void* l) {
    __builtin_amdgcn_global_load_lds(
        (const __attribute__((address_space(1))) unsigned int*)g,
        (__attribute__((address_space(3))) unsigned int*)l, 16, 0, 0);
}

__device__ __forceinline__ bf16x8 pack8(float4 a, float4 b) {
    ushort8 v;
    v[0] = f2bf(a.x); v[1] = f2bf(a.y); v[2] = f2bf(a.z); v[3] = f2bf(a.w);
    v[4] = f2bf(b.x); v[5] = f2bf(b.y); v[6] = f2bf(b.z); v[7] = f2bf(b.w);
    return __builtin_bit_cast(bf16x8, v);
}

// ---------------- main persistent kernel ----------------
__global__ __launch_bounds__(256, 1) void lstm_kernel(
    const float* __restrict__ xin,
    const float* __restrict__ tsp,
    const float* __restrict__ Ww, const float* __restrict__ Wb,
    const float* __restrict__ Uw, const float* __restrict__ Ub,
    const float* __restrict__ Dw, const float* __restrict__ Db,
    unsigned* __restrict__ hcbuf,      // [parity][group][16*512] u32
    unsigned* __restrict__ slots,      // [group][64] u32 (32 used)
    float* __restrict__ out)
{
    __shared__ ushort h_s[16 * 520];   // +8 shorts row pad
    __shared__ ushort c_s[16 * 520];
    __shared__ ushort x_s[16 * 264];   // bf16 x tile
    __shared__ float  x32_s[16 * 260]; // fp32 x staging
    __shared__ float  gb[4 * 256];     // gate preactivations
    __shared__ float  gd[4 * 256];     // W_d K-quarter partials
    __shared__ float  bias_g[64];
    __shared__ float  bias_d[16];

    const int tid  = threadIdx.x;
    const int lane = tid & 63;
    const int wv   = tid >> 6;         // wave id == gate id
    const int n    = lane & 15;
    const int quad = lane >> 4;
    const int gq   = blockIdx.x & 7;   // batch group
    const int s    = blockIdx.x >> 3;  // column slice 0..31
    const int jj   = s * 16;

    // ---- stationary B-fragments ----
    bf16x8 bW[16], bU[8], bD[4];
    {
        const int Rw = wv * Hq + jj + n;
        #pragma unroll
        for (int kk = 0; kk < 16; ++kk) {
            const float4* p = (const float4*)(Ww + (size_t)Rw * Hq + kk * 32 + quad * 8);
            bW[kk] = pack8(p[0], p[1]);
        }
        #pragma unroll
        for (int kk = 0; kk < 8; ++kk) {
            const float4* p = (const float4*)(Uw + (size_t)Rw * Iq + kk * 32 + quad * 8);
            bU[kk] = pack8(p[0], p[1]);
        }
        const int Rd = jj + n;
        #pragma unroll
        for (int kq = 0; kq < 4; ++kq) {
            const float4* p = (const float4*)(Dw + (size_t)Rd * Hq + (wv * 4 + kq) * 32 + quad * 8);
            bD[kq] = pack8(p[0], p[1]);
        }
    }
    if (tid < 64)
        bias_g[tid] = Wb[(tid >> 4) * Hq + jj + (tid & 15)] + Ub[(tid >> 4) * Hq + jj + (tid & 15)];
    if (tid >= 64 && tid < 80)
        bias_d[tid - 64] = Db[jj + (tid - 64)];
    __syncthreads();

    float c_reg = 0.f;                 // fp32 cell state for (b=tid>>4, j=tid&15)
    const int b = tid >> 4, j = tid & 15;
    const int grow = gq * 16 + b;

    const ushort* hp = &h_s[n * 520 + quad * 8];
    const ushort* cp = &c_s[n * 520 + quad * 8];
    const ushort* xp = &x_s[n * 264 + quad * 8];

    unsigned* myslot = &slots[gq * 64 + s];
    unsigned* pollp  = &slots[gq * 64 + (lane & 31)];

    for (int t = 0; t < Sq; ++t) {
        float tt = tsp[(size_t)grow * Sq + t];

        // ---- issue x(t) fp32 staging (async to LDS) ----
        #pragma unroll
        for (int q = 0; q < 4; ++q) {
            int r = q * 4 + wv;
            gl_lds16(xin + ((size_t)(gq * 16 + r) * Sq + t) * Iq + lane * 4, &x32_s[r * 260]);
        }

        // ---- hc broadcast read: coalesced relaxed agent loads (L2-bypass) ----
        unsigned* hcsrc = hcbuf + ((size_t)(t & 1) * 8 + gq) * 8192;
        unsigned v[32];
        #pragma unroll
        for (int q = 0; q < 32; ++q)
            v[q] = __hip_atomic_load(hcsrc + q * 256 + tid, __ATOMIC_RELAXED, __HIP_MEMORY_SCOPE_AGENT);

        // unpack: element idx = q*256+tid -> row=q>>1, col=(q&1)*256+tid
        #pragma unroll
        for (int q = 0; q < 32; ++q) {
            const int row = q >> 1, col = ((q & 1) << 8) + tid;
            h_s[row * 520 + col] = (ushort)(v[q] & 0xFFFFu);
            c_s[row * 520 + col] = (ushort)(v[q] >> 16);
        }
        __syncthreads();   // drains gl_lds (vmcnt) + hc/ds writes

        // ---- convert fp32 x tile -> bf16 ----
        {
            const int rr = tid >> 4, seg = tid & 15;
            const float4* src = (const float4*)&x32_s[rr * 260 + seg * 16];
            float4 a0 = src[0], a1 = src[1], a2 = src[2], a3 = src[3];
            ushort8 v0, v1;
            v0[0] = f2bf(a0.x); v0[1] = f2bf(a0.y); v0[2] = f2bf(a0.z); v0[3] = f2bf(a0.w);
            v0[4] = f2bf(a1.x); v0[5] = f2bf(a1.y); v0[6] = f2bf(a1.z); v0[7] = f2bf(a1.w);
            v1[0] = f2bf(a2.x); v1[1] = f2bf(a2.y); v1[2] = f2bf(a2.z); v1[3] = f2bf(a2.w);
            v1[4] = f2bf(a3.x); v1[5] = f2bf(a3.y); v1[6] = f2bf(a3.z); v1[7] = f2bf(a3.w);
            *(ushort8*)&x_s[rr * 264 + seg * 16]     = v0;
            *(ushort8*)&x_s[rr * 264 + seg * 16 + 8] = v1;
        }
        __syncthreads();

        // ---- MFMA phase ----
        floatx4 accW = {0.f, 0.f, 0.f, 0.f};
        floatx4 accU = {0.f, 0.f, 0.f, 0.f};
        floatx4 accD = {0.f, 0.f, 0.f, 0.f};
        #pragma unroll
        for (int kk = 0; kk < 16; ++kk) {
            bf16x8 ah = *(const bf16x8*)(hp + kk * 32);
            accW = __builtin_amdgcn_mfma_f32_16x16x32_bf16(ah, bW[kk], accW, 0, 0, 0);
            if (kk < 8) {
                bf16x8 ax = *(const bf16x8*)(xp + kk * 32);
                accU = __builtin_amdgcn_mfma_f32_16x16x32_bf16(ax, bU[kk], accU, 0, 0, 0);
            }
            if ((kk >> 2) == wv) {
                bf16x8 ac = *(const bf16x8*)(cp + kk * 32);
                accD = __builtin_amdgcn_mfma_f32_16x16x32_bf16(ac, bD[kk & 3], accD, 0, 0, 0);
            }
        }
        accW += accU;

        #pragma unroll
        for (int r2 = 0; r2 < 4; ++r2) {
            gb[wv * 256 + (quad * 4 + r2) * 16 + n] = accW[r2];
            gd[wv * 256 + (quad * 4 + r2) * 16 + n] = accD[r2];
        }
        __syncthreads();

        // ---- gate math ----
        float pf = gb[tid]       + bias_g[j];
        float pi = gb[256 + tid] + bias_g[16 + j];
        float po = gb[512 + tid] + bias_g[32 + j];
        float pc = gb[768 + tid] + bias_g[48 + j];
        float csum = gd[tid] + gd[256 + tid] + gd[512 + tid] + gd[768 + tid] + bias_d[j];
        float c_s1  = tanh_fast(csum);
        float c_adj = c_reg - c_s1 + c_s1 * tt;
        float fg = sigm(pf), ig = sigm(pi), og = sigm(po), cg = sigm(pc);
        float c_new = fg * c_adj + ig * cg;
        float h_new = og * tanh_fast(c_new);
        c_reg = c_new;

        out[((size_t)grow * Sq + t) * Hq + jj + j] = h_new;
        unsigned* hcdst = hcbuf + ((size_t)((t + 1) & 1) * 8 + gq) * 8192;
        unsigned hc = ((unsigned)f2bf(c_new) << 16) | (unsigned)f2bf(h_new);
        __hip_atomic_store(hcdst + b * 512 + jj + j, hc, __ATOMIC_RELAXED, __HIP_MEMORY_SCOPE_AGENT);
        __syncthreads();   // vmcnt(0) drain: hc stores ack'd at coherence point

        // ---- per-group flag barrier (slot per block, parallel poll) ----
        if (t < Sq - 1) {
            unsigned tgt = (unsigned)(t + 1);
            if (tid == 0)
                __hip_atomic_store(myslot, tgt, __ATOMIC_RELAXED, __HIP_MEMORY_SCOPE_AGENT);
            if (wv == 0) {
                for (;;) {
                    unsigned vv = __hip_atomic_load(pollp, __ATOMIC_RELAXED, __HIP_MEMORY_SCOPE_AGENT);
                    if (__all(vv >= tgt)) break;
                    __builtin_amdgcn_s_sleep(2);
                }
            }
            __syncthreads();
        }
    }
}

extern "C" void kernel_launch(void* const* d_in, const int* in_sizes, int n_in,
                              void* d_out, int out_size, void* d_ws, size_t ws_size,
                              hipStream_t stream) {
    const float* inputs = (const float*)d_in[0];
    const float* tsp    = (const float*)d_in[1];
    const float* Ww     = (const float*)d_in[2];
    const float* Wb     = (const float*)d_in[3];
    const float* Uw     = (const float*)d_in[4];
    const float* Ub     = (const float*)d_in[5];
    const float* Dw     = (const float*)d_in[6];
    const float* Db     = (const float*)d_in[7];
    float* out = (float*)d_out;

    char* ws = (char*)d_ws;
    // layout: [0, 512K) hcbuf (2 parities x 8 groups x 8192 u32) | [512K, 512K+2K) slots
    unsigned* hcbuf = (unsigned*)ws;
    unsigned* slots = (unsigned*)(ws + 524288);

    hipMemsetAsync(ws, 0, 262144, stream);          // parity-0 hc = 0 (h0 = c0 = 0)
    hipMemsetAsync(ws + 524288, 0, 2048, stream);   // slots = 0

    lstm_kernel<<<dim3(256), dim3(256), 0, stream>>>(
        inputs, tsp, Ww, Wb, Uw, Ub, Dw, Db, hcbuf, slots, out);
}